// Round 4
// baseline (382.032 us; speedup 1.0000x reference)
//
#include <hip/hip_runtime.h>

// Causal MHA fwd: B=2, N=2048, H=16, D=64. fp32 inputs, fp32 output.
// All tensors flat row-major (B*H, N, 64) (reference's reshape is a pure
// reinterpretation). Flash attention, one wave per 16 q rows.
//
// MFMA: gfx950-verified __builtin_amdgcn_mfma_f32_16x16x32_bf16.
//   A layout: A[m=lane&15][k=(lane>>4)*8 + j]
//   B layout: B[k=(lane>>4)*8 + j][n=lane&15]
//   C/D     : D[row=(lane>>4)*4 + r][col=lane&15]
//
// S-trick: compute S^T = K·Q^T so D holds S^T[key][q]; P is moved to the
// PV A-operand layout with a 16-shfl in-register transform (no LDS).

typedef short  short8v __attribute__((ext_vector_type(8)));
typedef float  float4v __attribute__((ext_vector_type(4)));
typedef float  float8v __attribute__((ext_vector_type(8)));

#define NQ 2048
#define DD 64

static __device__ __forceinline__ unsigned short f2bf(float x) {
    union { float f; unsigned int u; } v;
    v.f = x;
    return (unsigned short)((v.u + 0x7fffu + ((v.u >> 16) & 1u)) >> 16);  // RNE
}

static __device__ __forceinline__ short8v cvt8(const float* p) {
    float8v f = *(const float8v*)p;
    short8v r;
#pragma unroll
    for (int j = 0; j < 8; ++j) r[j] = (short)f2bf(f[j]);
    return r;
}

__global__ __launch_bounds__(256) void mha_fwd_kernel(
    const float* __restrict__ Kg,
    const float* __restrict__ Qg,
    const float* __restrict__ Vg,
    float* __restrict__ Og)
{
    const int lane = threadIdx.x & 63;
    const int wave = threadIdx.x >> 6;
    const int col  = lane & 15;
    const int quad = lane >> 4;

    const int bh = blockIdx.y;                    // b*H + h
    const int q0 = blockIdx.x * 64 + wave * 16;   // 16 q rows per wave

    const size_t base = (size_t)bh * NQ * DD;
    const float* Qp = Qg + base;
    const float* Kp = Kg + base;
    const float* Vp = Vg + base;

    const float sscale = 0.125f * 1.4426950408889634f;  // 1/sqrt(64) * log2(e)
    const int qg = q0 + col;                            // this lane's q (stats role)

    // Q as B-operand of S^T = K·Q^T: B[k=d-dim][n=q]. Two K=32 chunks.
    short8v qf[2];
#pragma unroll
    for (int c = 0; c < 2; ++c)
        qf[c] = cvt8(Qp + (size_t)(q0 + col) * DD + c * 32 + quad * 8);

    float m_i = -3.0e38f;
    float l_i = 0.0f;
    float4v o[4];
#pragma unroll
    for (int d = 0; d < 4; ++d) o[d] = (float4v){0.f, 0.f, 0.f, 0.f};

    for (int kb = 0; kb < q0 + 16; kb += 32) {
        // ---- two S^T tiles: keys [kb,kb+16) and [kb+16,kb+32) ----
        float4v s0 = (float4v){0.f, 0.f, 0.f, 0.f};
        float4v s1 = (float4v){0.f, 0.f, 0.f, 0.f};
#pragma unroll
        for (int c = 0; c < 2; ++c) {
            short8v kf0 = cvt8(Kp + (size_t)(kb + col) * DD + c * 32 + quad * 8);
            short8v kf1 = cvt8(Kp + (size_t)(kb + 16 + col) * DD + c * 32 + quad * 8);
            s0 = __builtin_amdgcn_mfma_f32_16x16x32_bf16(kf0, qf[c], s0, 0, 0, 0);
            s1 = __builtin_amdgcn_mfma_f32_16x16x32_bf16(kf1, qf[c], s1, 0, 0, 0);
        }

        // scale + causal mask (false for interior blocks)
        float sc0[4], sc1[4];
#pragma unroll
        for (int r = 0; r < 4; ++r) {
            const int key0 = kb + quad * 4 + r;
            sc0[r] = (key0 > qg) ? -3.0e38f : s0[r] * sscale;
            sc1[r] = (key0 + 16 > qg) ? -3.0e38f : s1[r] * sscale;
        }

        // ---- online softmax over 32 keys (per q = col) ----
        float mx = sc0[0];
#pragma unroll
        for (int r = 1; r < 4; ++r) mx = fmaxf(mx, sc0[r]);
#pragma unroll
        for (int r = 0; r < 4; ++r) mx = fmaxf(mx, sc1[r]);
        mx = fmaxf(mx, __shfl_xor(mx, 16));
        mx = fmaxf(mx, __shfl_xor(mx, 32));
        const float m_new = fmaxf(m_i, mx);

        float p0[4], p1[4];
        float rs = 0.f;
#pragma unroll
        for (int r = 0; r < 4; ++r) {
            p0[r] = exp2f(sc0[r] - m_new);
            p1[r] = exp2f(sc1[r] - m_new);
            rs += p0[r] + p1[r];
        }
        rs += __shfl_xor(rs, 16);
        rs += __shfl_xor(rs, 32);

        const float alpha = exp2f(m_i - m_new);
        l_i = l_i * alpha + rs;
        m_i = m_new;

        // ---- P (C-layout, two 16-key tiles) -> A-layout (K=32) ----
        const int srcb = 32 * (quad & 1) + col;
        short8v pf;
#pragma unroll
        for (int j = 0; j < 4; ++j) {
            const float a0 = __shfl(p0[j], srcb, 64);
            const float a1 = __shfl(p1[j], srcb, 64);
            const float b0 = __shfl(p0[j], srcb + 16, 64);
            const float b1 = __shfl(p1[j], srcb + 16, 64);
            pf[j]     = (short)f2bf(quad < 2 ? a0 : a1);
            pf[4 + j] = (short)f2bf(quad < 2 ? b0 : b1);
        }

        // rescale O (row r holds q = q0 + quad*4 + r)
        float av[4];
#pragma unroll
        for (int r = 0; r < 4; ++r) av[r] = __shfl(alpha, quad * 4 + r, 64);
#pragma unroll
        for (int d = 0; d < 4; ++d) {
#pragma unroll
            for (int r = 0; r < 4; ++r) o[d][r] *= av[r];
        }

        // ---- O += P·V : B[k=quad*8+j][n=col] = V[kb+quad*8+j][d*16+col] ----
#pragma unroll
        for (int d = 0; d < 4; ++d) {
            short8v vf;
#pragma unroll
            for (int j = 0; j < 8; ++j)
                vf[j] = (short)f2bf(Vp[(size_t)(kb + quad * 8 + j) * DD + d * 16 + col]);
            o[d] = __builtin_amdgcn_mfma_f32_16x16x32_bf16(pf, vf, o[d], 0, 0, 0);
        }
    }

    // ---- epilogue: divide by l, store FP32 ----
    float lv[4];
#pragma unroll
    for (int r = 0; r < 4; ++r) lv[r] = 1.0f / __shfl(l_i, quad * 4 + r, 64);

    float* Op = Og + base;
#pragma unroll
    for (int r = 0; r < 4; ++r) {
#pragma unroll
        for (int d = 0; d < 4; ++d) {
            Op[(size_t)(q0 + quad * 4 + r) * DD + d * 16 + col] = o[d][r] * lv[r];
        }
    }
}

extern "C" void kernel_launch(void* const* d_in, const int* in_sizes, int n_in,
                              void* d_out, int out_size, void* d_ws, size_t ws_size,
                              hipStream_t stream) {
    const float* keys    = (const float*)d_in[0];
    const float* queries = (const float*)d_in[1];
    const float* values  = (const float*)d_in[2];
    float* out           = (float*)d_out;

    dim3 grid(NQ / 64, 2 * 16);  // (q-tiles, B*H)
    dim3 block(256, 1, 1);
    mha_fwd_kernel<<<grid, block, 0, stream>>>(keys, queries, values, out);
}

// Round 5
// 239.429 us; speedup vs baseline: 1.5956x; 1.5956x over previous
//
#include <hip/hip_runtime.h>

// Causal MHA fwd: B=2, N=2048, H=16, D=64. fp32 in / fp32 out.
// Tensors flat row-major (B*H, N, 64). Block-cooperative flash attention:
// 128 q rows per block (4 waves x 32 rows), 32-key tiles staged in LDS
// (K row-major bf16, V transposed bf16), shared by all 4 waves.
//
// MFMA: gfx950-verified __builtin_amdgcn_mfma_f32_16x16x32_bf16.
//   A: A[m=lane&15][k=(lane>>4)*8+j]   B: B[k=(lane>>4)*8+j][n=lane&15]
//   C/D: D[row=(lane>>4)*4+r][col=lane&15]
// S-trick: S^T = K.Q^T so P exits in C-layout and a 16-shfl transform puts
// it in PV A-layout (verified in round 4).

typedef short  short8v __attribute__((ext_vector_type(8)));
typedef float  float4v __attribute__((ext_vector_type(4)));
typedef float  float8v __attribute__((ext_vector_type(8)));

#define NQ 2048
#define DD 64
#define QTILE 128
#define KTILE 32
#define KPITCH 72   // Klds row pitch (bf16 elts), 144B = 16B-aligned
#define VPITCH 40   // Vt  row pitch (bf16 elts),  80B = 16B-aligned

static __device__ __forceinline__ unsigned short f2bf(float x) {
    union { float f; unsigned int u; } v;
    v.f = x;
    return (unsigned short)((v.u + 0x7fffu + ((v.u >> 16) & 1u)) >> 16);  // RNE
}

static __device__ __forceinline__ short8v cvt8(const float* p) {
    float8v f = *(const float8v*)p;
    short8v r;
#pragma unroll
    for (int j = 0; j < 8; ++j) r[j] = (short)f2bf(f[j]);
    return r;
}

__global__ __launch_bounds__(256) void mha_fwd_kernel(
    const float* __restrict__ Kg,
    const float* __restrict__ Qg,
    const float* __restrict__ Vg,
    float* __restrict__ Og)
{
    __shared__ __align__(16) unsigned short Klds[KTILE * KPITCH];  // 4.6 KB
    __shared__ __align__(16) unsigned short Vt[DD * VPITCH];       // 5.1 KB

    const int t    = threadIdx.x;
    const int lane = t & 63;
    const int wave = t >> 6;
    const int col  = lane & 15;
    const int quad = lane >> 4;

    const int bh  = blockIdx.y;
    const int q0b = blockIdx.x * QTILE;
    const int wq0 = q0b + wave * 32;          // wave's first q row

    const size_t base = (size_t)bh * NQ * DD;
    const float* Qp = Qg + base;
    const float* Kp = Kg + base;
    const float* Vp = Vg + base;

    const float sscale = 0.125f * 1.4426950408889634f;  // 1/sqrt(64)*log2(e)

    // Q fragments (B-operand of S^T=K.Q^T), 2 q-subtiles x 2 K=32 chunks
    short8v qf[2][2];
#pragma unroll
    for (int s = 0; s < 2; ++s)
#pragma unroll
        for (int c = 0; c < 2; ++c)
            qf[s][c] = cvt8(Qp + (size_t)(wq0 + s * 16 + col) * DD + c * 32 + quad * 8);

    float m_i[2] = {-3.0e38f, -3.0e38f};
    float l_i[2] = {0.0f, 0.0f};
    float4v o[2][4];
#pragma unroll
    for (int s = 0; s < 2; ++s)
#pragma unroll
        for (int d = 0; d < 4; ++d) o[s][d] = (float4v){0.f, 0.f, 0.f, 0.f};

    const int kr = t >> 3, kc = t & 7;   // K staging: row 0..31, col-group 0..7
    const int vd = t & 63, vg = t >> 6;  // V staging: d 0..63, key-group 0..3

    for (int kb = 0; kb < q0b + QTILE; kb += KTILE) {
        __syncthreads();  // previous iteration's LDS reads complete

        // ---- stage K tile (row-major bf16) ----
        short8v ks = cvt8(Kp + (size_t)(kb + kr) * DD + kc * 8);
        *(short8v*)&Klds[kr * KPITCH + kc * 8] = ks;

        // ---- stage V tile transposed: Vt[d][key] ----
        {
            short8v vs;
#pragma unroll
            for (int i = 0; i < 8; ++i)
                vs[i] = (short)f2bf(Vp[(size_t)(kb + vg * 8 + i) * DD + vd]);
            *(short8v*)&Vt[vd * VPITCH + vg * 8] = vs;
        }

        __syncthreads();  // staging visible

        if (kb > wq0) continue;  // wave-uniform: this wave is done computing

        // ---- LDS fragments (shared across both q-subtiles) ----
        short8v kf[2][2];
#pragma unroll
        for (int u = 0; u < 2; ++u)
#pragma unroll
            for (int c = 0; c < 2; ++c)
                kf[u][c] = *(const short8v*)&Klds[(u * 16 + col) * KPITCH + c * 32 + quad * 8];
        short8v vf[4];
#pragma unroll
        for (int d = 0; d < 4; ++d)
            vf[d] = *(const short8v*)&Vt[(d * 16 + col) * VPITCH + quad * 8];

#pragma unroll
        for (int s = 0; s < 2; ++s) {
            // ---- S^T tiles: keys [kb,kb+16) (u=0) and [kb+16,kb+32) (u=1) ----
            float4v s0 = (float4v){0.f, 0.f, 0.f, 0.f};
            float4v s1 = (float4v){0.f, 0.f, 0.f, 0.f};
            s0 = __builtin_amdgcn_mfma_f32_16x16x32_bf16(kf[0][0], qf[s][0], s0, 0, 0, 0);
            s0 = __builtin_amdgcn_mfma_f32_16x16x32_bf16(kf[0][1], qf[s][1], s0, 0, 0, 0);
            s1 = __builtin_amdgcn_mfma_f32_16x16x32_bf16(kf[1][0], qf[s][0], s1, 0, 0, 0);
            s1 = __builtin_amdgcn_mfma_f32_16x16x32_bf16(kf[1][1], qf[s][1], s1, 0, 0, 0);

            const int qg = wq0 + s * 16 + col;  // this lane's q (stats role)

            float sc0[4], sc1[4];
#pragma unroll
            for (int r = 0; r < 4; ++r) {
                const int key0 = kb + quad * 4 + r;
                sc0[r] = (key0 > qg) ? -3.0e38f : s0[r] * sscale;
                sc1[r] = (key0 + 16 > qg) ? -3.0e38f : s1[r] * sscale;
            }

            // ---- online softmax over 32 keys (per q = col) ----
            float mx = sc0[0];
#pragma unroll
            for (int r = 1; r < 4; ++r) mx = fmaxf(mx, sc0[r]);
#pragma unroll
            for (int r = 0; r < 4; ++r) mx = fmaxf(mx, sc1[r]);
            mx = fmaxf(mx, __shfl_xor(mx, 16));
            mx = fmaxf(mx, __shfl_xor(mx, 32));
            const float m_new = fmaxf(m_i[s], mx);

            float p0[4], p1[4];
            float rs = 0.f;
#pragma unroll
            for (int r = 0; r < 4; ++r) {
                p0[r] = exp2f(sc0[r] - m_new);
                p1[r] = exp2f(sc1[r] - m_new);
                rs += p0[r] + p1[r];
            }
            rs += __shfl_xor(rs, 16);
            rs += __shfl_xor(rs, 32);

            const float alpha = exp2f(m_i[s] - m_new);
            l_i[s] = l_i[s] * alpha + rs;
            m_i[s] = m_new;

            // ---- P (C-layout) -> PV A-layout (verified transform) ----
            const int srcb = 32 * (quad & 1) + col;
            short8v pf;
#pragma unroll
            for (int j = 0; j < 4; ++j) {
                const float a0 = __shfl(p0[j], srcb, 64);
                const float a1 = __shfl(p1[j], srcb, 64);
                const float b0 = __shfl(p0[j], srcb + 16, 64);
                const float b1 = __shfl(p1[j], srcb + 16, 64);
                pf[j]     = (short)f2bf(quad < 2 ? a0 : a1);
                pf[4 + j] = (short)f2bf(quad < 2 ? b0 : b1);
            }

            // rescale O (row r holds q = quad*4 + r within subtile)
            float av[4];
#pragma unroll
            for (int r = 0; r < 4; ++r) av[r] = __shfl(alpha, quad * 4 + r, 64);
#pragma unroll
            for (int d = 0; d < 4; ++d) {
#pragma unroll
                for (int r = 0; r < 4; ++r) o[s][d][r] *= av[r];
            }

            // ---- O += P.V ----
#pragma unroll
            for (int d = 0; d < 4; ++d)
                o[s][d] = __builtin_amdgcn_mfma_f32_16x16x32_bf16(pf, vf[d], o[s][d], 0, 0, 0);
        }
    }

    // ---- epilogue: divide by l, store fp32 ----
    float* Op = Og + base;
#pragma unroll
    for (int s = 0; s < 2; ++s) {
        float lv[4];
#pragma unroll
        for (int r = 0; r < 4; ++r) lv[r] = 1.0f / __shfl(l_i[s], quad * 4 + r, 64);
#pragma unroll
        for (int r = 0; r < 4; ++r) {
#pragma unroll
            for (int d = 0; d < 4; ++d) {
                Op[(size_t)(wq0 + s * 16 + quad * 4 + r) * DD + d * 16 + col] =
                    o[s][d][r] * lv[r];
            }
        }
    }
}

extern "C" void kernel_launch(void* const* d_in, const int* in_sizes, int n_in,
                              void* d_out, int out_size, void* d_ws, size_t ws_size,
                              hipStream_t stream) {
    const float* keys    = (const float*)d_in[0];
    const float* queries = (const float*)d_in[1];
    const float* values  = (const float*)d_in[2];
    float* out           = (float*)d_out;

    dim3 grid(NQ / QTILE, 2 * 16);  // (q-tiles, B*H)
    dim3 block(256, 1, 1);
    mha_fwd_kernel<<<grid, block, 0, stream>>>(keys, queries, values, out);
}

// Round 6
// 164.612 us; speedup vs baseline: 2.3208x; 1.4545x over previous
//
#include <hip/hip_runtime.h>

// Causal MHA fwd: B=2, N=2048, H=16, D=64. fp32 in / fp32 out.
// Tensors flat row-major (B*H, N, 64). Block-cooperative flash attention.
//
// Round 6: causal load-balancing + double-buffered staging.
//  - 64-row q-tiles; block processes the PAIR (31-pair, pair) so every block
//    does exactly 33 x 64-key iterations (perfect balance, 512 equal blocks).
//  - 4 waves x 16 q-rows; 64-key K/V tiles staged in LDS (K row-major bf16,
//    V transposed bf16), register-prefetch double buffering: next tile's
//    global loads are issued right after the staging barrier and remain in
//    flight during compute.
//
// MFMA: gfx950-verified __builtin_amdgcn_mfma_f32_16x16x32_bf16.
//   A: A[m=lane&15][k=(lane>>4)*8+j]   B: B[k=(lane>>4)*8+j][n=lane&15]
//   C/D: D[row=(lane>>4)*4+r][col=lane&15]
// S-trick: S^T = K.Q^T so P exits in C-layout; 16-shfl transform per 32 keys
// moves it to the PV A-layout (verified rounds 4-5).

typedef short  short8v __attribute__((ext_vector_type(8)));
typedef float  float4v __attribute__((ext_vector_type(4)));
typedef float  float8v __attribute__((ext_vector_type(8)));

#define NQ 2048
#define DD 64
#define QT 64          // q rows per tile (per block phase)
#define KT 64          // keys per iteration
#define KP 72          // Klds row pitch (bf16 elts), 144B, 16B-aligned
#define VP 72          // Vt row pitch
#define NPAIR 16       // 32 tiles/head -> 16 pairs

static __device__ __forceinline__ unsigned short f2bf(float x) {
    union { float f; unsigned int u; } v;
    v.f = x;
    return (unsigned short)((v.u + 0x7fffu + ((v.u >> 16) & 1u)) >> 16);  // RNE
}

static __device__ __forceinline__ short8v cvt8v(float8v f) {
    short8v r;
#pragma unroll
    for (int j = 0; j < 8; ++j) r[j] = (short)f2bf(f[j]);
    return r;
}

__global__ __launch_bounds__(256) void mha_fwd_kernel(
    const float* __restrict__ Kg,
    const float* __restrict__ Qg,
    const float* __restrict__ Vg,
    float* __restrict__ Og)
{
    __shared__ __align__(16) unsigned short Klds[KT * KP];  // 9216 B
    __shared__ __align__(16) unsigned short Vt[DD * VP];    // 9216 B

    const int t    = threadIdx.x;
    const int lane = t & 63;
    const int wave = t >> 6;
    const int col  = lane & 15;
    const int quad = lane >> 4;

    const int bh   = blockIdx.x / NPAIR;
    const int pair = blockIdx.x % NPAIR;

    const size_t base = (size_t)bh * NQ * DD;
    const float* Qp = Qg + base;
    const float* Kp = Kg + base;
    const float* Vp = Vg + base;
    float*       Op = Og + base;

    const float sscale = 0.125f * 1.4426950408889634f;  // 1/sqrt(64)*log2(e)

    // staging roles
    const int kr = t >> 2, kc = (t & 3) * 16;      // K: row 0..63, 16-elt col group
    const int vd = t & 63, vg = (t >> 6) * 16;     // V: d 0..63, 16-key group

    const int tiles[2] = {31 - pair, pair};        // heavy phase first

    for (int ph = 0; ph < 2; ++ph) {
        const int T    = tiles[ph];
        const int q0   = T * QT + wave * 16;       // wave's 16 q rows
        const int qg   = q0 + col;                 // lane's q (stats role)
        const int kmax = T * QT;                   // last k-tile base

        // Q fragments (B-operand of S^T=K.Q^T), two K=32 chunks
        short8v qf0 = cvt8v(*(const float8v*)(Qp + (size_t)(q0 + col) * DD + quad * 8));
        short8v qf1 = cvt8v(*(const float8v*)(Qp + (size_t)(q0 + col) * DD + 32 + quad * 8));

        float m_i = -3.0e38f;
        float l_i = 0.0f;
        float4v o[4];
#pragma unroll
        for (int d = 0; d < 4; ++d) o[d] = (float4v){0.f, 0.f, 0.f, 0.f};

        // ---- prologue: prefetch k-tile 0 into registers ----
        float8v ka = *(const float8v*)(Kp + (size_t)kr * DD + kc);
        float8v kb8 = *(const float8v*)(Kp + (size_t)kr * DD + kc + 8);
        float vr[16];
#pragma unroll
        for (int i = 0; i < 16; ++i) vr[i] = Vp[(size_t)(vg + i) * DD + vd];

        for (int kb = 0; kb <= kmax; kb += KT) {
            __syncthreads();  // prior compute's LDS reads (or prior phase) done

            // ---- write staged regs -> LDS ----
            *(short8v*)&Klds[kr * KP + kc]     = cvt8v(ka);
            *(short8v*)&Klds[kr * KP + kc + 8] = cvt8v(kb8);
            {
                short8v v0, v1;
#pragma unroll
                for (int i = 0; i < 8; ++i) {
                    v0[i] = (short)f2bf(vr[i]);
                    v1[i] = (short)f2bf(vr[8 + i]);
                }
                *(short8v*)&Vt[vd * VP + vg]     = v0;
                *(short8v*)&Vt[vd * VP + vg + 8] = v1;
            }

            __syncthreads();  // staging visible

            // ---- issue next tile's global loads (in flight during compute) ----
            const int nkb = kb + KT;
            if (nkb <= kmax) {
                ka  = *(const float8v*)(Kp + (size_t)(nkb + kr) * DD + kc);
                kb8 = *(const float8v*)(Kp + (size_t)(nkb + kr) * DD + kc + 8);
#pragma unroll
                for (int i = 0; i < 16; ++i)
                    vr[i] = Vp[(size_t)(nkb + vg + i) * DD + vd];
            }

            // ---- LDS fragments ----
            short8v kf[4][2], vf[4][2];
#pragma unroll
            for (int u = 0; u < 4; ++u) {
                kf[u][0] = *(const short8v*)&Klds[(u * 16 + col) * KP + quad * 8];
                kf[u][1] = *(const short8v*)&Klds[(u * 16 + col) * KP + 32 + quad * 8];
            }
#pragma unroll
            for (int d = 0; d < 4; ++d) {
                vf[d][0] = *(const short8v*)&Vt[(d * 16 + col) * VP + quad * 8];
                vf[d][1] = *(const short8v*)&Vt[(d * 16 + col) * VP + 32 + quad * 8];
            }

            // ---- S^T tiles (4 x 16 keys) ----
            float4v sT[4];
#pragma unroll
            for (int u = 0; u < 4; ++u) sT[u] = (float4v){0.f, 0.f, 0.f, 0.f};
#pragma unroll
            for (int u = 0; u < 4; ++u) {
                sT[u] = __builtin_amdgcn_mfma_f32_16x16x32_bf16(kf[u][0], qf0, sT[u], 0, 0, 0);
                sT[u] = __builtin_amdgcn_mfma_f32_16x16x32_bf16(kf[u][1], qf1, sT[u], 0, 0, 0);
            }

            // ---- scale + causal mask + online softmax over 64 keys ----
            float p[4][4];
            float mx = -3.0e38f;
#pragma unroll
            for (int u = 0; u < 4; ++u)
#pragma unroll
                for (int r = 0; r < 4; ++r) {
                    const int key = kb + u * 16 + quad * 4 + r;
                    p[u][r] = (key > qg) ? -3.0e38f : sT[u][r] * sscale;
                    mx = fmaxf(mx, p[u][r]);
                }
            mx = fmaxf(mx, __shfl_xor(mx, 16));
            mx = fmaxf(mx, __shfl_xor(mx, 32));
            const float m_new = fmaxf(m_i, mx);

            float rs = 0.f;
#pragma unroll
            for (int u = 0; u < 4; ++u)
#pragma unroll
                for (int r = 0; r < 4; ++r) {
                    p[u][r] = exp2f(p[u][r] - m_new);
                    rs += p[u][r];
                }
            rs += __shfl_xor(rs, 16);
            rs += __shfl_xor(rs, 32);

            const float alpha = exp2f(m_i - m_new);
            l_i = l_i * alpha + rs;
            m_i = m_new;

            // ---- P (C-layout) -> PV A-layout, 2 chunks of 32 keys ----
            const int srcb = 32 * (quad & 1) + col;
            short8v pf0, pf1;
#pragma unroll
            for (int j = 0; j < 4; ++j) {
                float a0 = __shfl(p[0][j], srcb, 64);
                float a1 = __shfl(p[1][j], srcb, 64);
                float b0 = __shfl(p[0][j], srcb + 16, 64);
                float b1 = __shfl(p[1][j], srcb + 16, 64);
                pf0[j]     = (short)f2bf(quad < 2 ? a0 : a1);
                pf0[4 + j] = (short)f2bf(quad < 2 ? b0 : b1);
                a0 = __shfl(p[2][j], srcb, 64);
                a1 = __shfl(p[3][j], srcb, 64);
                b0 = __shfl(p[2][j], srcb + 16, 64);
                b1 = __shfl(p[3][j], srcb + 16, 64);
                pf1[j]     = (short)f2bf(quad < 2 ? a0 : a1);
                pf1[4 + j] = (short)f2bf(quad < 2 ? b0 : b1);
            }

            // rescale O (row r holds q = quad*4+r), then PV
            float av[4];
#pragma unroll
            for (int r = 0; r < 4; ++r) av[r] = __shfl(alpha, quad * 4 + r, 64);
#pragma unroll
            for (int d = 0; d < 4; ++d) {
#pragma unroll
                for (int r = 0; r < 4; ++r) o[d][r] *= av[r];
                o[d] = __builtin_amdgcn_mfma_f32_16x16x32_bf16(pf0, vf[d][0], o[d], 0, 0, 0);
                o[d] = __builtin_amdgcn_mfma_f32_16x16x32_bf16(pf1, vf[d][1], o[d], 0, 0, 0);
            }
        }

        // ---- epilogue: divide by l, store fp32 ----
        float lv[4];
#pragma unroll
        for (int r = 0; r < 4; ++r) lv[r] = 1.0f / __shfl(l_i, quad * 4 + r, 64);
#pragma unroll
        for (int r = 0; r < 4; ++r)
#pragma unroll
            for (int d = 0; d < 4; ++d)
                Op[(size_t)(q0 + quad * 4 + r) * DD + d * 16 + col] = o[d][r] * lv[r];
    }
}

extern "C" void kernel_launch(void* const* d_in, const int* in_sizes, int n_in,
                              void* d_out, int out_size, void* d_ws, size_t ws_size,
                              hipStream_t stream) {
    const float* keys    = (const float*)d_in[0];
    const float* queries = (const float*)d_in[1];
    const float* values  = (const float*)d_in[2];
    float* out           = (float*)d_out;

    dim3 grid(2 * 16 * NPAIR);  // 512 equal-work blocks
    dim3 block(256, 1, 1);
    mha_fwd_kernel<<<grid, block, 0, stream>>>(keys, queries, values, out);
}

// Round 7
// 140.743 us; speedup vs baseline: 2.7144x; 1.1696x over previous
//
#include <hip/hip_runtime.h>

// Causal MHA fwd: B=2, N=2048, H=16, D=64. fp32 in / fp32 out.
// Tensors flat row-major (B*H, N, 64). Block-cooperative flash attention.
//
// Round 7:
//  - PV via v_mfma_f32_16x16x16_bf16 (_1k builtin): P exits S^T=K.Q^T in
//    C-layout [key=quad*4+r][q=col], which IS the K=16 A-operand layout
//    (m=q=lane&15, k=key=(lane>>4)*4+j) -> P transform eliminated.
//  - Packed f32->bf16 via v_add 0x8000 + v_perm_b32 (round-half-up).
//  - Scale folded into Q at load; causal mask only in last (uniform) iter.
//  - XCD swizzle: all 16 pair-blocks of a head on one XCD for L2 reuse.
//  - Pair load-balance (33 iters/block) + register-prefetch dbuf (round 6).

typedef short  short4v __attribute__((ext_vector_type(4)));
typedef short  short8v __attribute__((ext_vector_type(8)));
typedef float  float4v __attribute__((ext_vector_type(4)));
typedef float  float8v __attribute__((ext_vector_type(8)));

#define NQ 2048
#define DD 64
#define QT 64          // q rows per tile (per block phase)
#define KT 64          // keys per iteration
#define KP 72          // Klds row pitch (bf16 elts), 144B, 16B-aligned
#define VP 72          // Vt row pitch
#define NPAIR 16       // 32 tiles/head -> 16 pairs

union U2 { unsigned int u[2]; short4v s; };
union U4 { unsigned int u[4]; short8v s; };

// pack two f32 into two bf16 (lo -> elt0), round-half-up via +0x8000
static __device__ __forceinline__ unsigned int pkbf(float lo, float hi) {
    unsigned int a = __builtin_bit_cast(unsigned int, hi) + 0x8000u;
    unsigned int b = __builtin_bit_cast(unsigned int, lo) + 0x8000u;
    return __builtin_amdgcn_perm(a, b, 0x07060302);
}

static __device__ __forceinline__ short8v pk8(float8v f) {
    U4 w;
#pragma unroll
    for (int i = 0; i < 4; ++i) w.u[i] = pkbf(f[2 * i], f[2 * i + 1]);
    return w.s;
}

__global__ __launch_bounds__(256) void mha_fwd_kernel(
    const float* __restrict__ Kg,
    const float* __restrict__ Qg,
    const float* __restrict__ Vg,
    float* __restrict__ Og)
{
    __shared__ __align__(16) unsigned short Klds[KT * KP];  // 9216 B
    __shared__ __align__(16) unsigned short Vt[DD * VP];    // 9216 B

    const int t    = threadIdx.x;
    const int lane = t & 63;
    const int wave = t >> 6;
    const int col  = lane & 15;
    const int quad = lane >> 4;

    // XCD swizzle: head's 16 pair-blocks all land on one XCD (blockIdx%8).
    const int b    = blockIdx.x;
    const int bh   = (b & 7) * 4 + ((b >> 3) & 3);
    const int pair = b >> 5;

    const size_t base = (size_t)bh * NQ * DD;
    const float* Qp = Qg + base;
    const float* Kp = Kg + base;
    const float* Vp = Vg + base;
    float*       Op = Og + base;

    const float sscale = 0.125f * 1.4426950408889634f;  // 1/sqrt(64)*log2(e)

    // staging roles
    const int kr = t >> 2, kc = (t & 3) * 16;      // K: row 0..63, 16-elt col group
    const int vd = t & 63, vg = (t >> 6) * 16;     // V: d 0..63, 16-key group

    const int tiles[2] = {31 - pair, pair};        // heavy phase first

    for (int ph = 0; ph < 2; ++ph) {
        const int T    = tiles[ph];
        const int q0   = T * QT + wave * 16;       // wave's 16 q rows
        const int qg   = q0 + col;                 // lane's q (stats role)
        const int kmax = T * QT;                   // last k-tile base

        // Q fragments (B-operand of S^T=K.Q^T), scale pre-folded
        short8v qf0, qf1;
        {
            float8v q0v = *(const float8v*)(Qp + (size_t)(q0 + col) * DD + quad * 8);
            float8v q1v = *(const float8v*)(Qp + (size_t)(q0 + col) * DD + 32 + quad * 8);
#pragma unroll
            for (int i = 0; i < 8; ++i) { q0v[i] *= sscale; q1v[i] *= sscale; }
            qf0 = pk8(q0v);
            qf1 = pk8(q1v);
        }

        float m_i = -3.0e38f;
        float l_i = 0.0f;
        float4v o[4];
#pragma unroll
        for (int d = 0; d < 4; ++d) o[d] = (float4v){0.f, 0.f, 0.f, 0.f};

        // ---- prologue: prefetch k-tile 0 into registers ----
        float8v ka  = *(const float8v*)(Kp + (size_t)kr * DD + kc);
        float8v kb8 = *(const float8v*)(Kp + (size_t)kr * DD + kc + 8);
        float vr[16];
#pragma unroll
        for (int i = 0; i < 16; ++i) vr[i] = Vp[(size_t)(vg + i) * DD + vd];

        for (int kb = 0; kb <= kmax; kb += KT) {
            __syncthreads();  // prior compute's LDS reads done

            // ---- staged regs -> LDS (packed cvt) ----
            *(short8v*)&Klds[kr * KP + kc]     = pk8(ka);
            *(short8v*)&Klds[kr * KP + kc + 8] = pk8(kb8);
            {
                U4 w0, w1;
#pragma unroll
                for (int i = 0; i < 4; ++i) {
                    w0.u[i] = pkbf(vr[2 * i], vr[2 * i + 1]);
                    w1.u[i] = pkbf(vr[8 + 2 * i], vr[9 + 2 * i]);
                }
                *(short8v*)&Vt[vd * VP + vg]     = w0.s;
                *(short8v*)&Vt[vd * VP + vg + 8] = w1.s;
            }

            __syncthreads();  // staging visible

            // ---- issue next tile's global loads (in flight during compute) ----
            const int nkb = kb + KT;
            if (nkb <= kmax) {
                ka  = *(const float8v*)(Kp + (size_t)(nkb + kr) * DD + kc);
                kb8 = *(const float8v*)(Kp + (size_t)(nkb + kr) * DD + kc + 8);
#pragma unroll
                for (int i = 0; i < 16; ++i)
                    vr[i] = Vp[(size_t)(nkb + vg + i) * DD + vd];
            }

            // ---- K fragments + S^T tiles (4 x 16 keys) ----
            float4v sT[4];
#pragma unroll
            for (int u = 0; u < 4; ++u) {
                short8v kf0 = *(const short8v*)&Klds[(u * 16 + col) * KP + quad * 8];
                short8v kf1 = *(const short8v*)&Klds[(u * 16 + col) * KP + 32 + quad * 8];
                sT[u] = (float4v){0.f, 0.f, 0.f, 0.f};
                sT[u] = __builtin_amdgcn_mfma_f32_16x16x32_bf16(kf0, qf0, sT[u], 0, 0, 0);
                sT[u] = __builtin_amdgcn_mfma_f32_16x16x32_bf16(kf1, qf1, sT[u], 0, 0, 0);
            }

            // ---- causal mask only on the (uniform) diagonal iteration ----
            if (kb == kmax) {
#pragma unroll
                for (int u = 0; u < 4; ++u)
#pragma unroll
                    for (int r = 0; r < 4; ++r) {
                        const int key = kb + u * 16 + quad * 4 + r;
                        if (key > qg) sT[u][r] = -3.0e38f;
                    }
            }

            // ---- online softmax over 64 keys (per q = col) ----
            float mx = sT[0][0];
#pragma unroll
            for (int u = 0; u < 4; ++u)
#pragma unroll
                for (int r = 0; r < 4; ++r) mx = fmaxf(mx, sT[u][r]);
            mx = fmaxf(mx, __shfl_xor(mx, 16));
            mx = fmaxf(mx, __shfl_xor(mx, 32));
            const float m_new = fmaxf(m_i, mx);

            float rs = 0.f;
#pragma unroll
            for (int u = 0; u < 4; ++u)
#pragma unroll
                for (int r = 0; r < 4; ++r) {
                    sT[u][r] = exp2f(sT[u][r] - m_new);
                    rs += sT[u][r];
                }
            rs += __shfl_xor(rs, 16);
            rs += __shfl_xor(rs, 32);

            const float alpha = exp2f(m_i - m_new);
            l_i = l_i * alpha + rs;
            m_i = m_new;

            // ---- pack P: C-layout IS the K=16 A-operand layout ----
            short4v pf[4];
#pragma unroll
            for (int u = 0; u < 4; ++u) {
                U2 w;
                w.u[0] = pkbf(sT[u][0], sT[u][1]);
                w.u[1] = pkbf(sT[u][2], sT[u][3]);
                pf[u] = w.s;
            }

            // rescale O (row r holds q = quad*4+r), then PV (4 x K=16 MFMA)
            float av[4];
#pragma unroll
            for (int r = 0; r < 4; ++r) av[r] = __shfl(alpha, quad * 4 + r, 64);
#pragma unroll
            for (int d = 0; d < 4; ++d) {
#pragma unroll
                for (int r = 0; r < 4; ++r) o[d][r] *= av[r];
#pragma unroll
                for (int u = 0; u < 4; ++u) {
                    short4v vf = *(const short4v*)&Vt[(d * 16 + col) * VP + u * 16 + quad * 4];
                    o[d] = __builtin_amdgcn_mfma_f32_16x16x16bf16_1k(pf[u], vf, o[d], 0, 0, 0);
                }
            }
        }

        // ---- epilogue: divide by l, store fp32 ----
        float lv[4];
#pragma unroll
        for (int r = 0; r < 4; ++r) lv[r] = 1.0f / __shfl(l_i, quad * 4 + r, 64);
#pragma unroll
        for (int r = 0; r < 4; ++r)
#pragma unroll
            for (int d = 0; d < 4; ++d)
                Op[(size_t)(q0 + quad * 4 + r) * DD + d * 16 + col] = o[d][r] * lv[r];
    }
}

extern "C" void kernel_launch(void* const* d_in, const int* in_sizes, int n_in,
                              void* d_out, int out_size, void* d_ws, size_t ws_size,
                              hipStream_t stream) {
    const float* keys    = (const float*)d_in[0];
    const float* queries = (const float*)d_in[1];
    const float* values  = (const float*)d_in[2];
    float* out           = (float*)d_out;

    dim3 grid(2 * 16 * NPAIR);  // 512 equal-work blocks
    dim3 block(256, 1, 1);
    mha_fwd_kernel<<<grid, block, 0, stream>>>(keys, queries, values, out);
}